// Round 1
// baseline (1961.312 us; speedup 1.0000x reference)
//
#include <hip/hip_runtime.h>

#define DD 8
#define HH 64
#define NSTEPS 8
#define NBATCH 16384

__device__ __forceinline__ float fast_tanh(float x) {
    // tanh(x) = 1 - 2/(exp(2x)+1); handles +-inf overflow correctly (-> +-1)
    float e2 = __expf(2.0f * x);
    return 1.0f - 2.0f * __builtin_amdgcn_rcpf(e2 + 1.0f);
}

// E[a][b] = W2[a][b] * sum_{i<8} W1[i][a] * W3[b][i]   (sample-independent)
__global__ void cnf_compute_E(const float* __restrict__ W1,
                              const float* __restrict__ W2,
                              const float* __restrict__ W3,
                              float* __restrict__ E) {
    int idx = blockIdx.x * blockDim.x + threadIdx.x;
    if (idx < HH * HH) {
        int a = idx >> 6, b = idx & 63;
        float g = 0.0f;
#pragma unroll
        for (int i = 0; i < DD; ++i) g += W1[i * HH + a] * W3[b * DD + i];
        E[idx] = W2[idx] * g;
    }
}

// Block: 256 threads = 4 waves, 64 samples (sample = lane within wave).
// Wave w owns hidden units [16w, 16w+16). Cross-wave via LDS.
__global__ __launch_bounds__(256) void cnf_main(
    const float* __restrict__ Xin,
    const float* __restrict__ W1, const float* __restrict__ b1,
    const float* __restrict__ W2, const float* __restrict__ b2,
    const float* __restrict__ W3, const float* __restrict__ b3,
    const float* __restrict__ E,
    float* __restrict__ out)
{
    const int tid = threadIdx.x;
    const int s   = tid & 63;                                  // sample within block
    const int w   = tid >> 6;                                  // wave id
    const int u0  = __builtin_amdgcn_readfirstlane(w << 4);    // force wave-uniform (SGPR)
    const int sample = blockIdx.x * 64 + s;

    __shared__ float h1s[HH][64];        // [unit][sample] — lane-consecutive, conflict-free
    __shared__ float d2s[HH][64];
    __shared__ float dxp[4][DD][64];     // per-wave partial dx
    __shared__ float trp[4][64];         // per-wave partial trace

    float x[DD];
#pragma unroll
    for (int i = 0; i < DD; ++i) x[i] = Xin[sample * DD + i];
    float logdet = 0.0f;
    const float dt = 1.0f / NSTEPS;

    float k1[DD], k2[DD], k3[DD], k4[DD], k5[DD];

    for (int step = 0; step < NSTEPS; ++step) {
        const float t0 = step * dt;
        float xacc[DD];
#pragma unroll
        for (int i = 0; i < DD; ++i) xacc[i] = x[i];
        float trsum = 0.0f;

        for (int st = 0; st < 6; ++st) {      // runtime loop keeps code in I$
            // ---- stage input (compile-time k indexing per uniform branch) ----
            float xs[DD];
            float tst;
            if (st == 0) {
                tst = t0;
#pragma unroll
                for (int i = 0; i < DD; ++i) xs[i] = x[i];
            } else if (st == 1) {
                tst = t0 + 0.2f * dt;
#pragma unroll
                for (int i = 0; i < DD; ++i) xs[i] = x[i] + dt * (0.2f * k1[i]);
            } else if (st == 2) {
                tst = t0 + 0.3f * dt;
#pragma unroll
                for (int i = 0; i < DD; ++i)
                    xs[i] = x[i] + dt * (3.0f/40.0f * k1[i] + 9.0f/40.0f * k2[i]);
            } else if (st == 3) {
                tst = t0 + 0.8f * dt;
#pragma unroll
                for (int i = 0; i < DD; ++i)
                    xs[i] = x[i] + dt * (44.0f/45.0f * k1[i] - 56.0f/15.0f * k2[i]
                                         + 32.0f/9.0f * k3[i]);
            } else if (st == 4) {
                tst = t0 + (8.0f/9.0f) * dt;
#pragma unroll
                for (int i = 0; i < DD; ++i)
                    xs[i] = x[i] + dt * (19372.0f/6561.0f * k1[i] - 25360.0f/2187.0f * k2[i]
                                         + 64448.0f/6561.0f * k3[i] - 212.0f/729.0f * k4[i]);
            } else {
                tst = t0 + dt;
#pragma unroll
                for (int i = 0; i < DD; ++i)
                    xs[i] = x[i] + dt * (9017.0f/3168.0f * k1[i] - 355.0f/33.0f * k2[i]
                                         + 46732.0f/5247.0f * k3[i] + 49.0f/176.0f * k4[i]
                                         - 5103.0f/18656.0f * k5[i]);
            }

            // ---- layer 1: h1 = tanh([xs,t] @ W1 + b1), own 16 units ----
            float d1own[16];
#pragma unroll
            for (int uu = 0; uu < 16; ++uu) {
                const int u = u0 + uu;
                float acc = b1[u] + tst * W1[8 * HH + u];
#pragma unroll
                for (int i = 0; i < DD; ++i) acc += xs[i] * W1[i * HH + u];
                float h = fast_tanh(acc);
                d1own[uu] = 1.0f - h * h;
                h1s[u][s] = h;
            }
            __syncthreads();   // h1 visible to all waves

            // ---- layer 2: h2 = tanh(h1 @ W2 + b2), own 16 units ----
            float h2acc[16];
#pragma unroll
            for (int vv = 0; vv < 16; ++vv) h2acc[vv] = b2[u0 + vv];
#pragma unroll
            for (int a = 0; a < HH; ++a) {
                float h1a = h1s[a][s];
#pragma unroll
                for (int vv = 0; vv < 16; ++vv)
                    h2acc[vv] += h1a * W2[a * HH + u0 + vv];
            }
#pragma unroll
            for (int vv = 0; vv < 16; ++vv) {
                float h = fast_tanh(h2acc[vv]);
                h2acc[vv] = h;
                d2s[u0 + vv][s] = 1.0f - h * h;
            }
            __syncthreads();   // d2 visible to all waves

            // ---- layer 3 partials: dx_i += sum_{v own} h2_v W3[v][i] ----
            float dxa[DD];
#pragma unroll
            for (int i = 0; i < DD; ++i) dxa[i] = 0.0f;
#pragma unroll
            for (int vv = 0; vv < 16; ++vv) {
                float h2v = h2acc[vv];
#pragma unroll
                for (int i = 0; i < DD; ++i)
                    dxa[i] += h2v * W3[(u0 + vv) * DD + i];
            }

            // ---- trace partial: sum_{a own} d1_a * sum_b E[a][b] d2_b ----
            float vacc[16];
#pragma unroll
            for (int aa = 0; aa < 16; ++aa) vacc[aa] = 0.0f;
#pragma unroll
            for (int b = 0; b < HH; ++b) {
                float d2b = d2s[b][s];
#pragma unroll
                for (int aa = 0; aa < 16; ++aa)
                    vacc[aa] += d2b * E[(u0 + aa) * HH + b];
            }
            float trown = 0.0f;
#pragma unroll
            for (int aa = 0; aa < 16; ++aa) trown += d1own[aa] * vacc[aa];

#pragma unroll
            for (int i = 0; i < DD; ++i) dxp[w][i][s] = dxa[i];
            trp[w][s] = trown;
            __syncthreads();   // partials visible

            // ---- cross-wave reduce (all waves redundantly) ----
            float dx[DD];
#pragma unroll
            for (int i = 0; i < DD; ++i)
                dx[i] = b3[i] + dxp[0][i][s] + dxp[1][i][s] + dxp[2][i][s] + dxp[3][i][s];
            float tr = trp[0][s] + trp[1][s] + trp[2][s] + trp[3][s];

            // ---- store k, accumulate solution ----
            if (st == 0) {
#pragma unroll
                for (int i = 0; i < DD; ++i) k1[i] = dx[i];
            } else if (st == 1) {
#pragma unroll
                for (int i = 0; i < DD; ++i) k2[i] = dx[i];
            } else if (st == 2) {
#pragma unroll
                for (int i = 0; i < DD; ++i) k3[i] = dx[i];
            } else if (st == 3) {
#pragma unroll
                for (int i = 0; i < DD; ++i) k4[i] = dx[i];
            } else if (st == 4) {
#pragma unroll
                for (int i = 0; i < DD; ++i) k5[i] = dx[i];
            }

            float bw;
            if (st == 0)      bw = 35.0f/384.0f;
            else if (st == 2) bw = 500.0f/1113.0f;
            else if (st == 3) bw = 125.0f/192.0f;
            else if (st == 4) bw = -2187.0f/6784.0f;
            else if (st == 5) bw = 11.0f/84.0f;
            else              bw = 0.0f;
            if (st != 1) {
#pragma unroll
                for (int i = 0; i < DD; ++i) xacc[i] += dt * bw * dx[i];
                trsum += bw * tr;
            }
        }

#pragma unroll
        for (int i = 0; i < DD; ++i) x[i] = xacc[i];
        logdet -= dt * trsum;   // f's last component is -trace
    }

    if (w == 0) {
#pragma unroll
        for (int i = 0; i < DD; ++i) out[sample * DD + i] = x[i];
        out[NBATCH * DD + sample] = logdet;
    }
}

extern "C" void kernel_launch(void* const* d_in, const int* in_sizes, int n_in,
                              void* d_out, int out_size, void* d_ws, size_t ws_size,
                              hipStream_t stream) {
    const float* x  = (const float*)d_in[0];
    const float* W1 = (const float*)d_in[1];
    const float* b1 = (const float*)d_in[2];
    const float* W2 = (const float*)d_in[3];
    const float* b2 = (const float*)d_in[4];
    const float* W3 = (const float*)d_in[5];
    const float* b3 = (const float*)d_in[6];
    float* outp = (float*)d_out;
    float* E    = (float*)d_ws;   // 64*64 floats = 16 KB

    hipLaunchKernelGGL(cnf_compute_E, dim3(16), dim3(256), 0, stream, W1, W2, W3, E);
    hipLaunchKernelGGL(cnf_main, dim3(NBATCH / 64), dim3(256), 0, stream,
                       x, W1, b1, W2, b2, W3, b3, E, outp);
}